// Round 1
// baseline (1323.045 us; speedup 1.0000x reference)
//
#include <hip/hip_runtime.h>
#include <hip/hip_bf16.h>

// Problem constants
#define Bz 1
#define Sq 256
#define Hd 4096
#define NH 128
#define Pd 64
#define Gg 8
#define Nn 128
#define Kc 4
#define D_INNER 8192            // NH*P
#define D_STATE 1024            // G*N
#define CONV_DIM 10240          // D_INNER + 2*D_STATE
#define IN_OUT 18560            // D_INNER + CONV_DIM + NH
#define EPSI 1e-6f

// ---------------- RMSNorm (input) ----------------
__global__ __launch_bounds__(256) void rmsnorm_k(const float* __restrict__ x,
                                                 const float* __restrict__ w,
                                                 float* __restrict__ h) {
  int s = blockIdx.x, t = threadIdx.x;
  const float4* row = reinterpret_cast<const float4*>(x + (size_t)s * Hd);
  const float4* wv  = reinterpret_cast<const float4*>(w);
  float4 v[4];
  float ss = 0.f;
#pragma unroll
  for (int i = 0; i < 4; i++) {
    v[i] = row[t + i * 256];
    ss += v[i].x * v[i].x + v[i].y * v[i].y + v[i].z * v[i].z + v[i].w * v[i].w;
  }
#pragma unroll
  for (int off = 32; off > 0; off >>= 1) ss += __shfl_xor(ss, off);
  __shared__ float red[4];
  if ((t & 63) == 0) red[t >> 6] = ss;
  __syncthreads();
  ss = red[0] + red[1] + red[2] + red[3];
  float scale = rsqrtf(ss * (1.f / (float)Hd) + EPSI);
  float4* ho = reinterpret_cast<float4*>(h + (size_t)s * Hd);
#pragma unroll
  for (int i = 0; i < 4; i++) {
    float4 wi = wv[t + i * 256];
    float4 o;
    o.x = v[i].x * scale * wi.x;
    o.y = v[i].y * scale * wi.y;
    o.z = v[i].z * scale * wi.z;
    o.w = v[i].w * scale * wi.w;
    ho[t + i * 256] = o;
  }
}

// ---------------- GEMM  C[M,N] = A[M,K] * B[N,K]^T (+ addend) ----------------
#define TS 64
#define TK 32
__global__ __launch_bounds__(256) void gemm_bt_f32(const float* __restrict__ A,
                                                   const float* __restrict__ B,
                                                   float* __restrict__ C,
                                                   const float* __restrict__ addend,
                                                   int M, int N, int K) {
  __shared__ float As[TK][TS + 4];
  __shared__ float Bs[TK][TS + 4];
  int t = threadIdx.x;
  int tx = t & 15, ty = t >> 4;
  int ty4 = ty * 4, tx4 = tx * 4;
  int rowBase = blockIdx.y * TS;
  int colBase = blockIdx.x * TS;

  int lr = t >> 2;          // 0..63 tile row for loading
  int lk = (t & 3) * 8;     // 0,8,16,24 k offset
  const float* Aload = A + (size_t)(rowBase + lr) * K + lk;
  const float* Bload = B + (size_t)(colBase + lr) * K + lk;

  float acc[4][4] = {};

  for (int k0 = 0; k0 < K; k0 += TK) {
    float4 a0 = *reinterpret_cast<const float4*>(Aload + k0);
    float4 a1 = *reinterpret_cast<const float4*>(Aload + k0 + 4);
    float4 b0 = *reinterpret_cast<const float4*>(Bload + k0);
    float4 b1 = *reinterpret_cast<const float4*>(Bload + k0 + 4);
    __syncthreads();
    As[lk + 0][lr] = a0.x; As[lk + 1][lr] = a0.y; As[lk + 2][lr] = a0.z; As[lk + 3][lr] = a0.w;
    As[lk + 4][lr] = a1.x; As[lk + 5][lr] = a1.y; As[lk + 6][lr] = a1.z; As[lk + 7][lr] = a1.w;
    Bs[lk + 0][lr] = b0.x; Bs[lk + 1][lr] = b0.y; Bs[lk + 2][lr] = b0.z; Bs[lk + 3][lr] = b0.w;
    Bs[lk + 4][lr] = b1.x; Bs[lk + 5][lr] = b1.y; Bs[lk + 6][lr] = b1.z; Bs[lk + 7][lr] = b1.w;
    __syncthreads();
#pragma unroll
    for (int kk = 0; kk < TK; ++kk) {
      float4 av = *reinterpret_cast<const float4*>(&As[kk][ty4]);
      float4 bv = *reinterpret_cast<const float4*>(&Bs[kk][tx4]);
      float a[4] = {av.x, av.y, av.z, av.w};
      float b[4] = {bv.x, bv.y, bv.z, bv.w};
#pragma unroll
      for (int r = 0; r < 4; r++)
#pragma unroll
        for (int c = 0; c < 4; c++) acc[r][c] += a[r] * b[c];
    }
  }

#pragma unroll
  for (int r = 0; r < 4; r++) {
    size_t idx = (size_t)(rowBase + ty4 + r) * N + colBase + tx4;
    float4 o = make_float4(acc[r][0], acc[r][1], acc[r][2], acc[r][3]);
    if (addend) {
      float4 ad = *reinterpret_cast<const float4*>(addend + idx);
      o.x += ad.x; o.y += ad.y; o.z += ad.z; o.w += ad.w;
    }
    *reinterpret_cast<float4*>(C + idx) = o;
  }
}

// ---------------- Conv (K=4) + SiLU ----------------
__global__ __launch_bounds__(256) void conv_silu_k(const float* __restrict__ proj,
                                                   const float* __restrict__ cstate,
                                                   const float* __restrict__ cw,
                                                   const float* __restrict__ cb,
                                                   float* __restrict__ y) {
  int c = blockIdx.x * 256 + threadIdx.x;  // 0..10239
  int s = blockIdx.y;                      // 0..255
  float acc = cb[c];
  float4 w4 = *reinterpret_cast<const float4*>(cw + c * 4);
  float wj[4] = {w4.x, w4.y, w4.z, w4.w};
#pragma unroll
  for (int j = 0; j < 4; j++) {
    int si = s + j - 3;
    float v = (si < 0) ? cstate[c * 3 + (si + 3)]
                       : proj[(size_t)si * IN_OUT + D_INNER + c];
    acc += wj[j] * v;
  }
  float sig = 1.f / (1.f + expf(-acc));
  y[(size_t)s * CONV_DIM + c] = acc * sig;
}

// ---------------- conv_state_out ----------------
__global__ __launch_bounds__(256) void conv_state_out_k(const float* __restrict__ proj,
                                                        float* __restrict__ out1) {
  int idx = blockIdx.x * 256 + threadIdx.x;  // < 30720
  int c = idx / 3, tt = idx % 3;
  out1[idx] = proj[(size_t)(Sq - 3 + tt) * IN_OUT + D_INNER + c];
}

// ---------------- dt -> softplus(dt + bias) ----------------
__global__ __launch_bounds__(256) void dt_k(const float* __restrict__ proj,
                                            const float* __restrict__ dt_bias,
                                            float* __restrict__ dtp) {
  int idx = blockIdx.x * 256 + threadIdx.x;  // 32768
  int s = idx >> 7, hh = idx & 127;
  float v = proj[(size_t)s * IN_OUT + D_INNER + CONV_DIM + hh] + dt_bias[hh];
  dtp[idx] = (v > 20.f) ? v : log1pf(expf(v));
}

// ---------------- SSM scan ----------------
// 128 blocks (one per head), 256 threads: thread t owns p = t>>2, n-block nb = t&3 (32 n each).
__global__ __launch_bounds__(256) void ssm_scan_k(const float* __restrict__ y_conv,
                                                  const float* __restrict__ dtp,
                                                  const float* __restrict__ ssm_state_in,
                                                  const float* __restrict__ A_log,
                                                  const float* __restrict__ D_param,
                                                  float* __restrict__ ys_out,
                                                  float* __restrict__ ssm_state_out) {
  int h = blockIdx.x;
  int t = threadIdx.x;
  int p = t >> 2;
  int nb = t & 3;
  int g = h >> 4;  // rep = NH/G = 16
  float A = -expf(A_log[h]);
  float Dp = D_param[h];

  float st[32];
  const float* sin_ = ssm_state_in + (((size_t)h * Pd + p) * Nn + nb * 32);
#pragma unroll
  for (int i = 0; i < 32; i++) st[i] = sin_[i];

  __shared__ float xs[64], Bsh[128], Csh[128];

  for (int s = 0; s < Sq; ++s) {
    __syncthreads();
    const float* row = y_conv + (size_t)s * CONV_DIM;
    if (t < 64) xs[t] = row[h * 64 + t];
    int n = t - 64;
    if (n >= 0 && n < 128) Bsh[n] = row[D_INNER + g * 128 + n];
    int m = t - 128;
    if (m >= 0) Csh[m] = row[D_INNER + D_STATE + g * 128 + m];
    __syncthreads();

    float dt = dtp[s * 128 + h];
    float dA = expf(dt * A);
    float x = xs[p];
    float dtx = dt * x;
    float ypart = 0.f;
#pragma unroll
    for (int i = 0; i < 32; i++) {
      float b = Bsh[nb * 32 + i];
      float c = Csh[nb * 32 + i];
      st[i] = st[i] * dA + dtx * b;
      ypart += st[i] * c;
    }
    ypart += __shfl_xor(ypart, 1);
    ypart += __shfl_xor(ypart, 2);
    if (nb == 0) ys_out[(size_t)s * D_INNER + h * 64 + p] = ypart + Dp * x;
  }

  float* sout = ssm_state_out + (((size_t)h * Pd + p) * Nn + nb * 32);
#pragma unroll
  for (int i = 0; i < 32; i++) sout[i] = st[i];
}

// ---------------- gate * silu + grouped RMSNorm (in-place on ys) ----------------
__global__ __launch_bounds__(256) void gated_norm_k(float* __restrict__ ys,
                                                    const float* __restrict__ proj,
                                                    const float* __restrict__ w) {
  int s = blockIdx.x, g = blockIdx.y, t = threadIdx.x;
  float vals[4];
  float ss = 0.f;
#pragma unroll
  for (int i = 0; i < 4; i++) {
    int d = g * 1024 + i * 256 + t;
    float gate = proj[(size_t)s * IN_OUT + d];
    float v = ys[(size_t)s * D_INNER + d] * (gate / (1.f + expf(-gate)));
    vals[i] = v;
    ss += v * v;
  }
#pragma unroll
  for (int off = 32; off > 0; off >>= 1) ss += __shfl_xor(ss, off);
  __shared__ float red[4];
  if ((t & 63) == 0) red[t >> 6] = ss;
  __syncthreads();
  ss = red[0] + red[1] + red[2] + red[3];
  float scale = rsqrtf(ss * (1.f / 1024.f) + EPSI);
#pragma unroll
  for (int i = 0; i < 4; i++) {
    int d = g * 1024 + i * 256 + t;
    ys[(size_t)s * D_INNER + d] = vals[i] * scale * w[d];
  }
}

extern "C" void kernel_launch(void* const* d_in, const int* in_sizes, int n_in,
                              void* d_out, int out_size, void* d_ws, size_t ws_size,
                              hipStream_t stream) {
  const float* hidden    = (const float*)d_in[0];
  const float* cstate_in = (const float*)d_in[1];
  const float* sstate_in = (const float*)d_in[2];
  const float* norm_w    = (const float*)d_in[3];
  const float* w_in      = (const float*)d_in[4];
  const float* conv_w    = (const float*)d_in[5];
  const float* conv_b    = (const float*)d_in[6];
  const float* A_log     = (const float*)d_in[7];
  const float* D_param   = (const float*)d_in[8];
  const float* dt_bias   = (const float*)d_in[9];
  const float* ssm_nw    = (const float*)d_in[10];
  const float* w_out     = (const float*)d_in[11];

  float* out0 = (float*)d_out;                    // [256,4096]
  float* out1 = out0 + (size_t)Sq * Hd;           // [10240,3]
  float* out2 = out1 + (size_t)CONV_DIM * 3;      // [128,64,128]

  float* ws = (float*)d_ws;
  float* h_buf  = ws;                                         // 1,048,576
  float* proj   = h_buf + (size_t)Sq * Hd;                    // 4,751,360
  float* y_conv = proj + (size_t)Sq * IN_OUT;                 // 2,621,440
  float* dtp    = y_conv + (size_t)Sq * CONV_DIM;             // 32,768
  float* ys     = dtp + (size_t)Sq * NH;                      // 2,097,152

  // 1. RMSNorm
  rmsnorm_k<<<Sq, 256, 0, stream>>>(hidden, norm_w, h_buf);
  // 2. in_proj: proj[256,18560] = h @ w_in^T
  gemm_bt_f32<<<dim3(IN_OUT / TS, Sq / TS), 256, 0, stream>>>(h_buf, w_in, proj, nullptr,
                                                              Sq, IN_OUT, Hd);
  // 3. conv + silu
  conv_silu_k<<<dim3(CONV_DIM / 256, Sq), 256, 0, stream>>>(proj, cstate_in, conv_w, conv_b, y_conv);
  // 4. conv_state_out
  conv_state_out_k<<<(CONV_DIM * 3) / 256, 256, 0, stream>>>(proj, out1);
  // 5. dt softplus
  dt_k<<<(Sq * NH) / 256, 256, 0, stream>>>(proj, dt_bias, dtp);
  // 6. SSM scan
  ssm_scan_k<<<NH, 256, 0, stream>>>(y_conv, dtp, sstate_in, A_log, D_param, ys, out2);
  // 7. gated + grouped RMSNorm (in-place)
  gated_norm_k<<<dim3(Sq, Gg), 256, 0, stream>>>(ys, proj, ssm_nw);
  // 8. out_proj + residual
  gemm_bt_f32<<<dim3(Hd / TS, Sq / TS), 256, 0, stream>>>(ys, w_out, out0, hidden,
                                                          Sq, Hd, D_INNER);
}

// Round 3
// 1192.660 us; speedup vs baseline: 1.1093x; 1.1093x over previous
//
#include <hip/hip_runtime.h>
#include <hip/hip_bf16.h>

// Problem constants
#define Sq 256
#define Hd 4096
#define NH 128
#define Pd 64
#define Gg 8
#define Nn 128
#define D_INNER 8192            // NH*P
#define D_STATE 1024            // G*N
#define CONV_DIM 10240          // D_INNER + 2*D_STATE
#define IN_OUT 18560            // D_INNER + CONV_DIM + NH
#define DT_COL0 18432           // D_INNER + CONV_DIM (start of dt columns)
#define EPSI 1e-6f

typedef _Float16 f16x8 __attribute__((ext_vector_type(8)));
typedef float f32x4 __attribute__((ext_vector_type(4)));

__device__ inline ushort f2h(float f) {
  _Float16 h = (_Float16)f;
  return __builtin_bit_cast(ushort, h);
}
__device__ inline ushort f2h_lo(float f, ushort hi) {
  float hf = (float)__builtin_bit_cast(_Float16, hi);
  _Float16 l = (_Float16)(f - hf);
  return __builtin_bit_cast(ushort, l);
}

// ---------------- RMSNorm (input) -> fp16 hi + lo ----------------
__global__ __launch_bounds__(256) void rmsnorm_k(const float* __restrict__ x,
                                                 const float* __restrict__ w,
                                                 ushort* __restrict__ h_hi,
                                                 ushort* __restrict__ h_lo) {
  int s = blockIdx.x, t = threadIdx.x;
  const float4* row = reinterpret_cast<const float4*>(x + (size_t)s * Hd);
  const float4* wv  = reinterpret_cast<const float4*>(w);
  float4 v[4];
  float ss = 0.f;
#pragma unroll
  for (int i = 0; i < 4; i++) {
    v[i] = row[t + i * 256];
    ss += v[i].x * v[i].x + v[i].y * v[i].y + v[i].z * v[i].z + v[i].w * v[i].w;
  }
#pragma unroll
  for (int off = 32; off > 0; off >>= 1) ss += __shfl_xor(ss, off);
  __shared__ float red[4];
  if ((t & 63) == 0) red[t >> 6] = ss;
  __syncthreads();
  ss = red[0] + red[1] + red[2] + red[3];
  float scale = rsqrtf(ss * (1.f / (float)Hd) + EPSI);
  ushort4* hh = reinterpret_cast<ushort4*>(h_hi + (size_t)s * Hd);
  ushort4* hl = reinterpret_cast<ushort4*>(h_lo + (size_t)s * Hd);
#pragma unroll
  for (int i = 0; i < 4; i++) {
    float4 wi = wv[t + i * 256];
    float f0 = v[i].x * scale * wi.x, f1 = v[i].y * scale * wi.y;
    float f2 = v[i].z * scale * wi.z, f3 = v[i].w * scale * wi.w;
    ushort4 oh, ol;
    oh.x = f2h(f0); ol.x = f2h_lo(f0, oh.x);
    oh.y = f2h(f1); ol.y = f2h_lo(f1, oh.y);
    oh.z = f2h(f2); ol.z = f2h_lo(f2, oh.z);
    oh.w = f2h(f3); ol.w = f2h_lo(f3, oh.w);
    hh[t + i * 256] = oh;
    hl[t + i * 256] = ol;
  }
}

// ---------------- MFMA GEMM  C[M,N] = A_f16[M,K] * f16(B_f32[N,K])^T (+addend) ----
// 256 threads = 4 waves. Wave w handles rows [w*BM/4, +BM/4).
// SPLIT: compensated product via hi/lo decomposition (3 MFMAs) ~ f32 precision.
template<int BM, int BN, bool SPLIT>
__global__ __launch_bounds__(256) void gemm_mfma_bt(const ushort* __restrict__ A_hi,
                                                    const ushort* __restrict__ A_lo,
                                                    const float* __restrict__ B,
                                                    float* __restrict__ C,
                                                    const float* __restrict__ addend,
                                                    int N, int K, int col0) {
  constexpr int BK = 32;
  constexpr int LDA = BK + 8;                 // 40 ushort = 80B stride
  constexpr int M_REP = BM / 64;
  constexpr int N_REP = BN / 16;
  __shared__ __align__(16) ushort As[BM * LDA];
  __shared__ __align__(16) ushort Bs[BN * LDA];
  __shared__ __align__(16) ushort AsL[SPLIT ? BM * LDA : 1];
  __shared__ __align__(16) ushort BsL[SPLIT ? BN * LDA : 1];

  int t = threadIdx.x;
  int wave = t >> 6, lane = t & 63;
  int rowBase = blockIdx.y * BM;
  int colBase = col0 + blockIdx.x * BN;
  int wrow = wave * (BM / 4);
  int frow = lane & 15, fk = (lane >> 4) * 8;

  f32x4 acc[M_REP][N_REP] = {};

  for (int k0 = 0; k0 < K; k0 += BK) {
    // ---- global loads into regs ----
    uint4 aval[BM / 64], avalL[SPLIT ? BM / 64 : 1];
#pragma unroll
    for (int it = 0; it < BM / 64; ++it) {
      int i = t + 256 * it;
      int row = i >> 2, k = (i & 3) * 8;
      aval[it] = *reinterpret_cast<const uint4*>(A_hi + (size_t)(rowBase + row) * K + k0 + k);
      if constexpr (SPLIT)
        avalL[it] = *reinterpret_cast<const uint4*>(A_lo + (size_t)(rowBase + row) * K + k0 + k);
    }
    float bv[8];
    int brow, bk, bnum;
    if constexpr (BN == 64) {
      brow = t >> 2; bk = (t & 3) * 8; bnum = 8;
      const float* bp = B + (size_t)(colBase + brow) * K + k0 + bk;
      float4 b0 = *reinterpret_cast<const float4*>(bp);
      float4 b1 = *reinterpret_cast<const float4*>(bp + 4);
      bv[0] = b0.x; bv[1] = b0.y; bv[2] = b0.z; bv[3] = b0.w;
      bv[4] = b1.x; bv[5] = b1.y; bv[6] = b1.z; bv[7] = b1.w;
    } else {  // BN == 32
      brow = t >> 3; bk = (t & 7) * 4; bnum = 4;
      const float* bp = B + (size_t)(colBase + brow) * K + k0 + bk;
      float4 b0 = *reinterpret_cast<const float4*>(bp);
      bv[0] = b0.x; bv[1] = b0.y; bv[2] = b0.z; bv[3] = b0.w;
    }
    __syncthreads();
    // ---- LDS writes ----
#pragma unroll
    for (int it = 0; it < BM / 64; ++it) {
      int i = t + 256 * it;
      int row = i >> 2, k = (i & 3) * 8;
      *reinterpret_cast<uint4*>(&As[row * LDA + k]) = aval[it];
      if constexpr (SPLIT)
        *reinterpret_cast<uint4*>(&AsL[row * LDA + k]) = avalL[it];
    }
    {
      ushort hb[8], lb[8];
#pragma unroll
      for (int j = 0; j < 8; ++j) {
        if (j < bnum) {
          hb[j] = f2h(bv[j]);
          if constexpr (SPLIT) lb[j] = f2h_lo(bv[j], hb[j]);
        }
      }
      if constexpr (BN == 64) {
        *reinterpret_cast<uint4*>(&Bs[brow * LDA + bk]) = *reinterpret_cast<uint4*>(hb);
        if constexpr (SPLIT)
          *reinterpret_cast<uint4*>(&BsL[brow * LDA + bk]) = *reinterpret_cast<uint4*>(lb);
      } else {
        *reinterpret_cast<ushort4*>(&Bs[brow * LDA + bk]) = *reinterpret_cast<ushort4*>(hb);
        if constexpr (SPLIT)
          *reinterpret_cast<ushort4*>(&BsL[brow * LDA + bk]) = *reinterpret_cast<ushort4*>(lb);
      }
    }
    __syncthreads();
    // ---- fragments + MFMA ----
    f16x8 af[M_REP], bf[N_REP];
    f16x8 afL[SPLIT ? M_REP : 1], bfL[SPLIT ? N_REP : 1];
#pragma unroll
    for (int m = 0; m < M_REP; ++m) {
      af[m] = *reinterpret_cast<const f16x8*>(&As[(wrow + m * 16 + frow) * LDA + fk]);
      if constexpr (SPLIT)
        afL[m] = *reinterpret_cast<const f16x8*>(&AsL[(wrow + m * 16 + frow) * LDA + fk]);
    }
#pragma unroll
    for (int n = 0; n < N_REP; ++n) {
      bf[n] = *reinterpret_cast<const f16x8*>(&Bs[(n * 16 + frow) * LDA + fk]);
      if constexpr (SPLIT)
        bfL[n] = *reinterpret_cast<const f16x8*>(&BsL[(n * 16 + frow) * LDA + fk]);
    }
#pragma unroll
    for (int m = 0; m < M_REP; ++m)
#pragma unroll
      for (int n = 0; n < N_REP; ++n) {
        acc[m][n] = __builtin_amdgcn_mfma_f32_16x16x32_f16(af[m], bf[n], acc[m][n], 0, 0, 0);
        if constexpr (SPLIT) {
          acc[m][n] = __builtin_amdgcn_mfma_f32_16x16x32_f16(af[m], bfL[n], acc[m][n], 0, 0, 0);
          acc[m][n] = __builtin_amdgcn_mfma_f32_16x16x32_f16(afL[m], bf[n], acc[m][n], 0, 0, 0);
        }
      }
  }

  // ---- epilogue: C/D layout col=lane&15, row=(lane>>4)*4+r ----
#pragma unroll
  for (int m = 0; m < M_REP; ++m) {
    int row0 = rowBase + wrow + m * 16 + (lane >> 4) * 4;
#pragma unroll
    for (int n = 0; n < N_REP; ++n) {
      int col = colBase + n * 16 + frow;
#pragma unroll
      for (int r = 0; r < 4; ++r) {
        size_t idx = (size_t)(row0 + r) * N + col;
        float v = acc[m][n][r];
        if (addend) v += addend[idx];
        C[idx] = v;
      }
    }
  }
}

// ---------------- Conv (K=4) + SiLU ----------------
__global__ __launch_bounds__(256) void conv_silu_k(const float* __restrict__ proj,
                                                   const float* __restrict__ cstate,
                                                   const float* __restrict__ cw,
                                                   const float* __restrict__ cb,
                                                   float* __restrict__ y) {
  int c = blockIdx.x * 256 + threadIdx.x;  // 0..10239
  int s = blockIdx.y;                      // 0..255
  float acc = cb[c];
  float4 w4 = *reinterpret_cast<const float4*>(cw + c * 4);
  float wj[4] = {w4.x, w4.y, w4.z, w4.w};
#pragma unroll
  for (int j = 0; j < 4; j++) {
    int si = s + j - 3;
    float v = (si < 0) ? cstate[c * 3 + (si + 3)]
                       : proj[(size_t)si * IN_OUT + D_INNER + c];
    acc += wj[j] * v;
  }
  float sig = 1.f / (1.f + expf(-acc));
  y[(size_t)s * CONV_DIM + c] = acc * sig;
}

// ---------------- conv_state_out ----------------
__global__ __launch_bounds__(256) void conv_state_out_k(const float* __restrict__ proj,
                                                        float* __restrict__ out1) {
  int idx = blockIdx.x * 256 + threadIdx.x;  // < 30720
  int c = idx / 3, tt = idx % 3;
  out1[idx] = proj[(size_t)(Sq - 3 + tt) * IN_OUT + D_INNER + c];
}

// ---------------- dt -> softplus(dt + bias) ----------------
__global__ __launch_bounds__(256) void dt_k(const float* __restrict__ proj,
                                            const float* __restrict__ dt_bias,
                                            float* __restrict__ dtp) {
  int idx = blockIdx.x * 256 + threadIdx.x;  // 32768
  int s = idx >> 7, hh = idx & 127;
  float v = proj[(size_t)s * IN_OUT + DT_COL0 + hh] + dt_bias[hh];
  dtp[idx] = (v > 20.f) ? v : log1pf(expf(v));
}

// ---------------- SSM scan (chunked LDS staging) ----------------
#define CS 16
__global__ __launch_bounds__(256) void ssm_scan_k(const float* __restrict__ y_conv,
                                                  const float* __restrict__ dtp,
                                                  const float* __restrict__ sstate_in,
                                                  const float* __restrict__ A_log,
                                                  const float* __restrict__ D_param,
                                                  float* __restrict__ ys_out,
                                                  float* __restrict__ sstate_out) {
  int h = blockIdx.x;
  int t = threadIdx.x;
  int ng = t & 7, p2 = t >> 3;
  int g = h >> 4;  // rep = NH/G = 16
  float A = -expf(A_log[h]);
  float Dp = D_param[h];

  float st0[16], st1[16];
  {
    const float* sp = sstate_in + ((size_t)h * Pd + p2 * 2) * Nn + ng * 16;
#pragma unroll
    for (int i = 0; i < 16; i += 4) {
      float4 v = *reinterpret_cast<const float4*>(sp + i);
      st0[i] = v.x; st0[i + 1] = v.y; st0[i + 2] = v.z; st0[i + 3] = v.w;
      float4 w = *reinterpret_cast<const float4*>(sp + Nn + i);
      st1[i] = w.x; st1[i + 1] = w.y; st1[i + 2] = w.z; st1[i + 3] = w.w;
    }
  }

  __shared__ float ybuf[CS][328];   // cols 0..63 = x, 64..191 = B, 192..319 = C
  __shared__ float dts[CS];
  int lr = t >> 4;       // 0..15 : chunk row this thread stages
  int lc = t & 15;       // f4-col worker

  for (int ch = 0; ch < Sq / CS; ++ch) {
    int s0 = ch * CS;
    __syncthreads();
    const float* rowp = y_conv + (size_t)(s0 + lr) * CONV_DIM;
#pragma unroll
    for (int j = 0; j < 5; ++j) {
      int c = lc + 16 * j;  // f4 index 0..79
      float4 v;
      if (c < 16)      v = *reinterpret_cast<const float4*>(rowp + h * 64 + c * 4);
      else if (c < 48) v = *reinterpret_cast<const float4*>(rowp + D_INNER + g * 128 + (c - 16) * 4);
      else             v = *reinterpret_cast<const float4*>(rowp + D_INNER + D_STATE + g * 128 + (c - 48) * 4);
      *reinterpret_cast<float4*>(&ybuf[lr][c * 4]) = v;
    }
    if (t < CS) dts[t] = dtp[(s0 + t) * NH + h];
    __syncthreads();

#pragma unroll 4
    for (int stp = 0; stp < CS; ++stp) {
      float dt = dts[stp];
      float dA = expf(dt * A);
      float x0 = ybuf[stp][p2 * 2], x1 = ybuf[stp][p2 * 2 + 1];
      float dtx0 = dt * x0, dtx1 = dt * x1;
      float y0 = 0.f, y1 = 0.f;
#pragma unroll
      for (int i = 0; i < 16; ++i) {
        float b = ybuf[stp][64 + ng * 16 + i];
        float c = ybuf[stp][192 + ng * 16 + i];
        st0[i] = st0[i] * dA + dtx0 * b; y0 += st0[i] * c;
        st1[i] = st1[i] * dA + dtx1 * b; y1 += st1[i] * c;
      }
      y0 += __shfl_xor(y0, 1); y0 += __shfl_xor(y0, 2); y0 += __shfl_xor(y0, 4);
      y1 += __shfl_xor(y1, 1); y1 += __shfl_xor(y1, 2); y1 += __shfl_xor(y1, 4);
      if (ng == 0) {
        float* o = ys_out + (size_t)(s0 + stp) * D_INNER + h * 64 + p2 * 2;
        o[0] = y0 + Dp * x0;
        o[1] = y1 + Dp * x1;
      }
    }
  }

  float* so = sstate_out + ((size_t)h * Pd + p2 * 2) * Nn + ng * 16;
#pragma unroll
  for (int i = 0; i < 16; i += 4) {
    *reinterpret_cast<float4*>(so + i)      = make_float4(st0[i], st0[i + 1], st0[i + 2], st0[i + 3]);
    *reinterpret_cast<float4*>(so + Nn + i) = make_float4(st1[i], st1[i + 1], st1[i + 2], st1[i + 3]);
  }
}

// ---------------- gate*silu + grouped RMSNorm -> fp16 ----------------
__global__ __launch_bounds__(256) void gated_norm_k(const float* __restrict__ ys,
                                                    const float* __restrict__ proj,
                                                    const float* __restrict__ w,
                                                    ushort* __restrict__ out_h) {
  int s = blockIdx.x, g = blockIdx.y, t = threadIdx.x;
  float vals[4];
  float ss = 0.f;
#pragma unroll
  for (int i = 0; i < 4; i++) {
    int d = g * 1024 + i * 256 + t;
    float gate = proj[(size_t)s * IN_OUT + d];
    float v = ys[(size_t)s * D_INNER + d] * (gate / (1.f + expf(-gate)));
    vals[i] = v;
    ss += v * v;
  }
#pragma unroll
  for (int off = 32; off > 0; off >>= 1) ss += __shfl_xor(ss, off);
  __shared__ float red[4];
  if ((t & 63) == 0) red[t >> 6] = ss;
  __syncthreads();
  ss = red[0] + red[1] + red[2] + red[3];
  float scale = rsqrtf(ss * (1.f / 1024.f) + EPSI);
#pragma unroll
  for (int i = 0; i < 4; i++) {
    int d = g * 1024 + i * 256 + t;
    out_h[(size_t)s * D_INNER + d] = f2h(vals[i] * scale * w[d]);
  }
}

extern "C" void kernel_launch(void* const* d_in, const int* in_sizes, int n_in,
                              void* d_out, int out_size, void* d_ws, size_t ws_size,
                              hipStream_t stream) {
  const float* hidden    = (const float*)d_in[0];
  const float* cstate_in = (const float*)d_in[1];
  const float* sstate_in = (const float*)d_in[2];
  const float* norm_w    = (const float*)d_in[3];
  const float* w_in      = (const float*)d_in[4];
  const float* conv_w    = (const float*)d_in[5];
  const float* conv_b    = (const float*)d_in[6];
  const float* A_log     = (const float*)d_in[7];
  const float* D_param   = (const float*)d_in[8];
  const float* dt_bias   = (const float*)d_in[9];
  const float* ssm_nw    = (const float*)d_in[10];
  const float* w_out     = (const float*)d_in[11];

  float* out0 = (float*)d_out;                    // [256,4096]
  float* out1 = out0 + (size_t)Sq * Hd;           // [10240,3]
  float* out2 = out1 + (size_t)CONV_DIM * 3;      // [128,64,128]

  ushort* h_hi  = (ushort*)d_ws;                              // 2 MB
  ushort* h_lo  = h_hi + (size_t)Sq * Hd;                     // 2 MB
  float* proj   = (float*)(h_lo + (size_t)Sq * Hd);           // 19 MB
  float* y_conv = proj + (size_t)Sq * IN_OUT;                 // 10.5 MB
  float* dtp    = y_conv + (size_t)Sq * CONV_DIM;             // 128 KB
  float* ys     = dtp + (size_t)Sq * NH;                      // 8 MB
  ushort* ys_h  = (ushort*)(ys + (size_t)Sq * D_INNER);       // 4 MB

  // 1. RMSNorm -> fp16 hi/lo
  rmsnorm_k<<<Sq, 256, 0, stream>>>(hidden, norm_w, h_hi, h_lo);
  // 2. in_proj: proj[256,18560] = h @ w_in^T (fp16 single-pass)
  gemm_mfma_bt<256, 64, false><<<dim3(IN_OUT / 64, 1), 256, 0, stream>>>(
      h_hi, nullptr, w_in, proj, nullptr, IN_OUT, Hd, 0);
  // 2b. dt columns fixup: split-precision (~f32) on cols 18432..18559
  gemm_mfma_bt<256, 64, true><<<dim3(2, 1), 256, 0, stream>>>(
      h_hi, h_lo, w_in, proj, nullptr, IN_OUT, Hd, DT_COL0);
  // 3. conv + silu
  conv_silu_k<<<dim3(CONV_DIM / 256, Sq), 256, 0, stream>>>(proj, cstate_in, conv_w, conv_b, y_conv);
  // 4. conv_state_out
  conv_state_out_k<<<(CONV_DIM * 3) / 256, 256, 0, stream>>>(proj, out1);
  // 5. dt softplus
  dt_k<<<(Sq * NH) / 256, 256, 0, stream>>>(proj, dt_bias, dtp);
  // 6. SSM scan
  ssm_scan_k<<<NH, 256, 0, stream>>>(y_conv, dtp, sstate_in, A_log, D_param, ys, out2);
  // 7. gated + grouped RMSNorm -> fp16 A for out_proj
  gated_norm_k<<<dim3(Sq, Gg), 256, 0, stream>>>(ys, proj, ssm_nw, ys_h);
  // 8. out_proj + residual
  gemm_mfma_bt<128, 32, false><<<dim3(Hd / 32, 2), 256, 0, stream>>>(
      ys_h, nullptr, w_out, out0, hidden, Hd, D_INNER, 0);
}

// Round 4
// 586.649 us; speedup vs baseline: 2.2553x; 2.0330x over previous
//
#include <hip/hip_runtime.h>
#include <hip/hip_bf16.h>

// Problem constants
#define Sq 256
#define Hd 4096
#define NH 128
#define Pd 64
#define Gg 8
#define Nn 128
#define D_INNER 8192            // NH*P
#define D_STATE 1024            // G*N
#define CONV_DIM 10240          // D_INNER + 2*D_STATE
#define IN_OUT 18560            // D_INNER + CONV_DIM + NH
#define DT_COL0 18432           // D_INNER + CONV_DIM (start of dt columns)
#define EPSI 1e-6f

typedef _Float16 f16x8 __attribute__((ext_vector_type(8)));
typedef float f32x4 __attribute__((ext_vector_type(4)));

__device__ inline ushort f2h(float f) {
  _Float16 h = (_Float16)f;
  return __builtin_bit_cast(ushort, h);
}
__device__ inline ushort f2h_lo(float f, ushort hi) {
  float hf = (float)__builtin_bit_cast(_Float16, hi);
  _Float16 l = (_Float16)(f - hf);
  return __builtin_bit_cast(ushort, l);
}

// ---------------- RMSNorm (input) -> fp16 hi + lo ----------------
__global__ __launch_bounds__(256) void rmsnorm_k(const float* __restrict__ x,
                                                 const float* __restrict__ w,
                                                 ushort* __restrict__ h_hi,
                                                 ushort* __restrict__ h_lo) {
  int s = blockIdx.x, t = threadIdx.x;
  const float4* row = reinterpret_cast<const float4*>(x + (size_t)s * Hd);
  const float4* wv  = reinterpret_cast<const float4*>(w);
  float4 v[4];
  float ss = 0.f;
#pragma unroll
  for (int i = 0; i < 4; i++) {
    v[i] = row[t + i * 256];
    ss += v[i].x * v[i].x + v[i].y * v[i].y + v[i].z * v[i].z + v[i].w * v[i].w;
  }
#pragma unroll
  for (int off = 32; off > 0; off >>= 1) ss += __shfl_xor(ss, off);
  __shared__ float red[4];
  if ((t & 63) == 0) red[t >> 6] = ss;
  __syncthreads();
  ss = red[0] + red[1] + red[2] + red[3];
  float scale = rsqrtf(ss * (1.f / (float)Hd) + EPSI);
  ushort4* hh = reinterpret_cast<ushort4*>(h_hi + (size_t)s * Hd);
  ushort4* hl = reinterpret_cast<ushort4*>(h_lo + (size_t)s * Hd);
#pragma unroll
  for (int i = 0; i < 4; i++) {
    float4 wi = wv[t + i * 256];
    float f0 = v[i].x * scale * wi.x, f1 = v[i].y * scale * wi.y;
    float f2 = v[i].z * scale * wi.z, f3 = v[i].w * scale * wi.w;
    ushort4 oh, ol;
    oh.x = f2h(f0); ol.x = f2h_lo(f0, oh.x);
    oh.y = f2h(f1); ol.y = f2h_lo(f1, oh.y);
    oh.z = f2h(f2); ol.z = f2h_lo(f2, oh.z);
    oh.w = f2h(f3); ol.w = f2h_lo(f3, oh.w);
    hh[t + i * 256] = oh;
    hl[t + i * 256] = ol;
  }
}

// ---------------- MFMA GEMM, BM=64 rows/block, reg-prefetch pipeline ----------
// C[M, ldc] (+z-partial) = A_f16[M,K] * f16(B_f32[N,K])^T
// grid: (x = N/BN col tiles, y = M/64 row tiles, z = split-K chunks of kLen)
template<int BN, bool SPLIT>
__global__ __launch_bounds__(256) void gemm_mfma(const ushort* __restrict__ A_hi,
                                                 const ushort* __restrict__ A_lo,
                                                 const float* __restrict__ B,
                                                 float* __restrict__ C,
                                                 int ldc, int K, int kLen,
                                                 int bcol0, int M) {
  constexpr int BK = 64;
  constexpr int LDA = 72;                       // f16 elems per LDS row (144B stride)
  constexpr int N_REP = BN / 32;                // per-wave 16-col tiles
  constexpr int BQN = (BN == 128) ? 8 : 4;      // float4 loads of B per thread
  __shared__ __align__(16) ushort As[64 * LDA];
  __shared__ __align__(16) ushort Bs[BN * LDA];
  __shared__ __align__(16) ushort AsL[SPLIT ? 64 * LDA : 1];
  __shared__ __align__(16) ushort BsL[SPLIT ? BN * LDA : 1];

  int t = threadIdx.x;
  int wave = t >> 6, lane = t & 63;
  int wr = wave >> 1, wc = wave & 1;
  int frow = lane & 15, fk = (lane >> 4) * 8;
  int rowBase = blockIdx.y * 64;
  int bcol = bcol0 + blockIdx.x * BN;           // row index into B
  int ccol = blockIdx.x * BN;                   // col index into C (compact)
  int kStart = blockIdx.z * kLen;
  C += (size_t)blockIdx.z * M * ldc;            // split-K partial plane

  int arow = t >> 2, ak = (t & 3) * 16;
  const ushort* Ap  = A_hi + (size_t)(rowBase + arow) * K + ak;
  const ushort* ApL = SPLIT ? (A_lo + (size_t)(rowBase + arow) * K + ak) : nullptr;

  int brow, bq;
  if constexpr (BN == 128) { brow = t >> 1; bq = (t & 1) * 32; }
  else                     { brow = t >> 2; bq = (t & 3) * 16; }
  const float* Bp = B + (size_t)(bcol + brow) * K + bq;

  f32x4 acc[2][N_REP] = {};
  uint4 aPre[2], aPreL[2];
  float4 bPre[BQN];

  auto loadK = [&](int kk) {
    aPre[0] = *reinterpret_cast<const uint4*>(Ap + kk);
    aPre[1] = *reinterpret_cast<const uint4*>(Ap + kk + 8);
    if constexpr (SPLIT) {
      aPreL[0] = *reinterpret_cast<const uint4*>(ApL + kk);
      aPreL[1] = *reinterpret_cast<const uint4*>(ApL + kk + 8);
    }
#pragma unroll
    for (int j = 0; j < BQN; ++j)
      bPre[j] = *reinterpret_cast<const float4*>(Bp + kk + j * 4);
  };

  loadK(kStart);
  for (int ki = 0; ki < kLen; ki += BK) {
    __syncthreads();
    // ---- LDS writes from prefetch regs ----
    *reinterpret_cast<uint4*>(&As[arow * LDA + ak])     = aPre[0];
    *reinterpret_cast<uint4*>(&As[arow * LDA + ak + 8]) = aPre[1];
    if constexpr (SPLIT) {
      *reinterpret_cast<uint4*>(&AsL[arow * LDA + ak])     = aPreL[0];
      *reinterpret_cast<uint4*>(&AsL[arow * LDA + ak + 8]) = aPreL[1];
    }
    {
      ushort hb[BQN * 4];
      ushort lb[SPLIT ? BQN * 4 : 1];
      const float* bf = reinterpret_cast<const float*>(bPre);
#pragma unroll
      for (int j = 0; j < BQN * 4; ++j) {
        hb[j] = f2h(bf[j]);
        if constexpr (SPLIT) lb[j] = f2h_lo(bf[j], hb[j]);
      }
#pragma unroll
      for (int j = 0; j < BQN / 2; ++j)
        *reinterpret_cast<uint4*>(&Bs[brow * LDA + bq + j * 8]) =
            reinterpret_cast<const uint4*>(hb)[j];
      if constexpr (SPLIT) {
#pragma unroll
        for (int j = 0; j < BQN / 2; ++j)
          *reinterpret_cast<uint4*>(&BsL[brow * LDA + bq + j * 8]) =
              reinterpret_cast<const uint4*>(lb)[j];
      }
    }
    __syncthreads();
    // ---- prefetch next K-step (overlaps frag reads + MFMA) ----
    if (ki + BK < kLen) loadK(kStart + ki + BK);
    // ---- fragments + MFMA ----
    f16x8 af[2][2], bfv[N_REP][2];
    f16x8 afL[SPLIT ? 2 : 1][2], bfL[SPLIT ? N_REP : 1][2];
#pragma unroll
    for (int m = 0; m < 2; ++m)
#pragma unroll
      for (int kh = 0; kh < 2; ++kh) {
        af[m][kh] = *reinterpret_cast<const f16x8*>(
            &As[(wr * 32 + m * 16 + frow) * LDA + kh * 32 + fk]);
        if constexpr (SPLIT)
          afL[m][kh] = *reinterpret_cast<const f16x8*>(
              &AsL[(wr * 32 + m * 16 + frow) * LDA + kh * 32 + fk]);
      }
#pragma unroll
    for (int n = 0; n < N_REP; ++n)
#pragma unroll
      for (int kh = 0; kh < 2; ++kh) {
        bfv[n][kh] = *reinterpret_cast<const f16x8*>(
            &Bs[(wc * (BN / 2) + n * 16 + frow) * LDA + kh * 32 + fk]);
        if constexpr (SPLIT)
          bfL[n][kh] = *reinterpret_cast<const f16x8*>(
              &BsL[(wc * (BN / 2) + n * 16 + frow) * LDA + kh * 32 + fk]);
      }
#pragma unroll
    for (int kh = 0; kh < 2; ++kh)
#pragma unroll
      for (int m = 0; m < 2; ++m)
#pragma unroll
        for (int n = 0; n < N_REP; ++n) {
          acc[m][n] = __builtin_amdgcn_mfma_f32_16x16x32_f16(af[m][kh], bfv[n][kh], acc[m][n], 0, 0, 0);
          if constexpr (SPLIT) {
            acc[m][n] = __builtin_amdgcn_mfma_f32_16x16x32_f16(af[m][kh], bfL[n][kh], acc[m][n], 0, 0, 0);
            acc[m][n] = __builtin_amdgcn_mfma_f32_16x16x32_f16(afL[m][kh], bfv[n][kh], acc[m][n], 0, 0, 0);
          }
        }
  }

  // ---- epilogue: C/D layout col=lane&15, row=(lane>>4)*4+r ----
#pragma unroll
  for (int m = 0; m < 2; ++m) {
    int row0 = rowBase + wr * 32 + m * 16 + (lane >> 4) * 4;
#pragma unroll
    for (int n = 0; n < N_REP; ++n) {
      int col = ccol + wc * (BN / 2) + n * 16 + frow;
#pragma unroll
      for (int r = 0; r < 4; ++r)
        C[(size_t)(row0 + r) * ldc + col] = acc[m][n][r];
    }
  }
}

// ---------------- Conv (K=4) + SiLU ----------------
__global__ __launch_bounds__(256) void conv_silu_k(const float* __restrict__ proj,
                                                   const float* __restrict__ cstate,
                                                   const float* __restrict__ cw,
                                                   const float* __restrict__ cb,
                                                   float* __restrict__ y) {
  int c = blockIdx.x * 256 + threadIdx.x;  // 0..10239
  int s = blockIdx.y;                      // 0..255
  float acc = cb[c];
  float4 w4 = *reinterpret_cast<const float4*>(cw + c * 4);
  float wj[4] = {w4.x, w4.y, w4.z, w4.w};
#pragma unroll
  for (int j = 0; j < 4; j++) {
    int si = s + j - 3;
    float v = (si < 0) ? cstate[c * 3 + (si + 3)]
                       : proj[(size_t)si * IN_OUT + D_INNER + c];
    acc += wj[j] * v;
  }
  float sig = 1.f / (1.f + expf(-acc));
  y[(size_t)s * CONV_DIM + c] = acc * sig;
}

// ---------------- conv_state_out ----------------
__global__ __launch_bounds__(256) void conv_state_out_k(const float* __restrict__ proj,
                                                        float* __restrict__ out1) {
  int idx = blockIdx.x * 256 + threadIdx.x;  // < 30720
  int c = idx / 3, tt = idx % 3;
  out1[idx] = proj[(size_t)(Sq - 3 + tt) * IN_OUT + D_INNER + c];
}

// ---------------- dt: reduce 4 split-K partials + bias -> softplus ----------------
__global__ __launch_bounds__(256) void dt_k(const float* __restrict__ dtfix,
                                            const float* __restrict__ dt_bias,
                                            float* __restrict__ dtp) {
  int idx = blockIdx.x * 256 + threadIdx.x;  // 32768 = 256*128
  int hh = idx & 127;
  float v = dtfix[idx] + dtfix[32768 + idx] + dtfix[65536 + idx] + dtfix[98304 + idx]
            + dt_bias[hh];
  dtp[idx] = (v > 20.f) ? v : log1pf(expf(v));
}

// ---------------- SSM scan (chunked LDS staging) ----------------
#define CS 16
__global__ __launch_bounds__(256) void ssm_scan_k(const float* __restrict__ y_conv,
                                                  const float* __restrict__ dtp,
                                                  const float* __restrict__ sstate_in,
                                                  const float* __restrict__ A_log,
                                                  const float* __restrict__ D_param,
                                                  float* __restrict__ ys_out,
                                                  float* __restrict__ sstate_out) {
  int h = blockIdx.x;
  int t = threadIdx.x;
  int ng = t & 7, p2 = t >> 3;
  int g = h >> 4;  // rep = NH/G = 16
  float A = -expf(A_log[h]);
  float Dp = D_param[h];

  float st0[16], st1[16];
  {
    const float* sp = sstate_in + ((size_t)h * Pd + p2 * 2) * Nn + ng * 16;
#pragma unroll
    for (int i = 0; i < 16; i += 4) {
      float4 v = *reinterpret_cast<const float4*>(sp + i);
      st0[i] = v.x; st0[i + 1] = v.y; st0[i + 2] = v.z; st0[i + 3] = v.w;
      float4 w = *reinterpret_cast<const float4*>(sp + Nn + i);
      st1[i] = w.x; st1[i + 1] = w.y; st1[i + 2] = w.z; st1[i + 3] = w.w;
    }
  }

  __shared__ float ybuf[CS][328];   // cols 0..63 = x, 64..191 = B, 192..319 = C
  __shared__ float dts[CS];
  int lr = t >> 4;       // 0..15 : chunk row this thread stages
  int lc = t & 15;       // f4-col worker

  for (int ch = 0; ch < Sq / CS; ++ch) {
    int s0 = ch * CS;
    __syncthreads();
    const float* rowp = y_conv + (size_t)(s0 + lr) * CONV_DIM;
#pragma unroll
    for (int j = 0; j < 5; ++j) {
      int c = lc + 16 * j;  // f4 index 0..79
      float4 v;
      if (c < 16)      v = *reinterpret_cast<const float4*>(rowp + h * 64 + c * 4);
      else if (c < 48) v = *reinterpret_cast<const float4*>(rowp + D_INNER + g * 128 + (c - 16) * 4);
      else             v = *reinterpret_cast<const float4*>(rowp + D_INNER + D_STATE + g * 128 + (c - 48) * 4);
      *reinterpret_cast<float4*>(&ybuf[lr][c * 4]) = v;
    }
    if (t < CS) dts[t] = dtp[(s0 + t) * NH + h];
    __syncthreads();

#pragma unroll 4
    for (int stp = 0; stp < CS; ++stp) {
      float dt = dts[stp];
      float dA = expf(dt * A);
      float x0 = ybuf[stp][p2 * 2], x1 = ybuf[stp][p2 * 2 + 1];
      float dtx0 = dt * x0, dtx1 = dt * x1;
      float y0 = 0.f, y1 = 0.f;
#pragma unroll
      for (int i = 0; i < 16; ++i) {
        float b = ybuf[stp][64 + ng * 16 + i];
        float c = ybuf[stp][192 + ng * 16 + i];
        st0[i] = st0[i] * dA + dtx0 * b; y0 += st0[i] * c;
        st1[i] = st1[i] * dA + dtx1 * b; y1 += st1[i] * c;
      }
      y0 += __shfl_xor(y0, 1); y0 += __shfl_xor(y0, 2); y0 += __shfl_xor(y0, 4);
      y1 += __shfl_xor(y1, 1); y1 += __shfl_xor(y1, 2); y1 += __shfl_xor(y1, 4);
      if (ng == 0) {
        float* o = ys_out + (size_t)(s0 + stp) * D_INNER + h * 64 + p2 * 2;
        o[0] = y0 + Dp * x0;
        o[1] = y1 + Dp * x1;
      }
    }
  }

  float* so = sstate_out + ((size_t)h * Pd + p2 * 2) * Nn + ng * 16;
#pragma unroll
  for (int i = 0; i < 16; i += 4) {
    *reinterpret_cast<float4*>(so + i)      = make_float4(st0[i], st0[i + 1], st0[i + 2], st0[i + 3]);
    *reinterpret_cast<float4*>(so + Nn + i) = make_float4(st1[i], st1[i + 1], st1[i + 2], st1[i + 3]);
  }
}

// ---------------- gate*silu + grouped RMSNorm -> fp16 ----------------
__global__ __launch_bounds__(256) void gated_norm_k(const float* __restrict__ ys,
                                                    const float* __restrict__ proj,
                                                    const float* __restrict__ w,
                                                    ushort* __restrict__ out_h) {
  int s = blockIdx.x, g = blockIdx.y, t = threadIdx.x;
  float vals[4];
  float ss = 0.f;
#pragma unroll
  for (int i = 0; i < 4; i++) {
    int d = g * 1024 + i * 256 + t;
    float gate = proj[(size_t)s * IN_OUT + d];
    float v = ys[(size_t)s * D_INNER + d] * (gate / (1.f + expf(-gate)));
    vals[i] = v;
    ss += v * v;
  }
#pragma unroll
  for (int off = 32; off > 0; off >>= 1) ss += __shfl_xor(ss, off);
  __shared__ float red[4];
  if ((t & 63) == 0) red[t >> 6] = ss;
  __syncthreads();
  ss = red[0] + red[1] + red[2] + red[3];
  float scale = rsqrtf(ss * (1.f / 1024.f) + EPSI);
#pragma unroll
  for (int i = 0; i < 4; i++) {
    int d = g * 1024 + i * 256 + t;
    out_h[(size_t)s * D_INNER + d] = f2h(vals[i] * scale * w[d]);
  }
}

// ---------------- out reduce: out0 = p0 + p1 + hidden ----------------
__global__ __launch_bounds__(256) void reduce_out_k(const float* __restrict__ p0,
                                                    const float* __restrict__ p1,
                                                    const float* __restrict__ hidden,
                                                    float* __restrict__ out0) {
  int i = blockIdx.x * 256 + threadIdx.x;   // f4 index, 262144 total
  float4 a = reinterpret_cast<const float4*>(p0)[i];
  float4 b = reinterpret_cast<const float4*>(p1)[i];
  float4 c = reinterpret_cast<const float4*>(hidden)[i];
  float4 o;
  o.x = a.x + b.x + c.x; o.y = a.y + b.y + c.y;
  o.z = a.z + b.z + c.z; o.w = a.w + b.w + c.w;
  reinterpret_cast<float4*>(out0)[i] = o;
}

extern "C" void kernel_launch(void* const* d_in, const int* in_sizes, int n_in,
                              void* d_out, int out_size, void* d_ws, size_t ws_size,
                              hipStream_t stream) {
  const float* hidden    = (const float*)d_in[0];
  const float* cstate_in = (const float*)d_in[1];
  const float* sstate_in = (const float*)d_in[2];
  const float* norm_w    = (const float*)d_in[3];
  const float* w_in      = (const float*)d_in[4];
  const float* conv_w    = (const float*)d_in[5];
  const float* conv_b    = (const float*)d_in[6];
  const float* A_log     = (const float*)d_in[7];
  const float* D_param   = (const float*)d_in[8];
  const float* dt_bias   = (const float*)d_in[9];
  const float* ssm_nw    = (const float*)d_in[10];
  const float* w_out     = (const float*)d_in[11];

  float* out0 = (float*)d_out;                    // [256,4096]
  float* out1 = out0 + (size_t)Sq * Hd;           // [10240,3]
  float* out2 = out1 + (size_t)CONV_DIM * 3;      // [128,64,128]

  ushort* h_hi  = (ushort*)d_ws;                              // 2 MB
  ushort* h_lo  = h_hi + (size_t)Sq * Hd;                     // 2 MB
  float* proj   = (float*)(h_lo + (size_t)Sq * Hd);           // 19 MB
  float* y_conv = proj + (size_t)Sq * IN_OUT;                 // 10.5 MB
  float* dtp    = y_conv + (size_t)Sq * CONV_DIM;             // 128 KB
  float* ys     = dtp + (size_t)Sq * NH;                      // 8 MB
  ushort* ys_h  = (ushort*)(ys + (size_t)Sq * D_INNER);       // 4 MB
  float* dtfix  = (float*)(ys_h + (size_t)Sq * D_INNER);      // 4*256*128 = 512 KB
  float* oppart = dtfix + 4 * Sq * NH;                        // 2*256*4096 = 8 MB

  // 1. RMSNorm -> fp16 hi/lo
  rmsnorm_k<<<Sq, 256, 0, stream>>>(hidden, norm_w, h_hi, h_lo);
  // 2. in_proj: proj[256,18560] = h @ w_in^T   (580 blocks, reg-prefetch)
  gemm_mfma<128, false><<<dim3(IN_OUT / 128, 4, 1), 256, 0, stream>>>(
      h_hi, nullptr, w_in, proj, IN_OUT, Hd, Hd, 0, Sq);
  // 2b. dt columns, compensated fp16 (~f32), split-K x4 -> dtfix partials
  gemm_mfma<128, true><<<dim3(1, 4, 4), 256, 0, stream>>>(
      h_hi, h_lo, w_in, dtfix, NH, Hd, Hd / 4, DT_COL0, Sq);
  // 3. conv + silu
  conv_silu_k<<<dim3(CONV_DIM / 256, Sq), 256, 0, stream>>>(proj, cstate_in, conv_w, conv_b, y_conv);
  // 4. conv_state_out
  conv_state_out_k<<<(CONV_DIM * 3) / 256, 256, 0, stream>>>(proj, out1);
  // 5. dt: reduce partials + softplus
  dt_k<<<(Sq * NH) / 256, 256, 0, stream>>>(dtfix, dt_bias, dtp);
  // 6. SSM scan
  ssm_scan_k<<<NH, 256, 0, stream>>>(y_conv, dtp, sstate_in, A_log, D_param, ys, out2);
  // 7. gated + grouped RMSNorm -> fp16 A for out_proj
  gated_norm_k<<<dim3(Sq, Gg), 256, 0, stream>>>(ys, proj, ssm_nw, ys_h);
  // 8. out_proj split-K x2 -> partials (512 blocks)
  gemm_mfma<64, false><<<dim3(Hd / 64, 4, 2), 256, 0, stream>>>(
      ys_h, nullptr, w_out, oppart, Hd, D_INNER, D_INNER / 2, 0, Sq);
  // 9. reduce + residual
  reduce_out_k<<<(Sq * Hd / 4) / 256, 256, 0, stream>>>(
      oppart, oppart + (size_t)Sq * Hd, hidden, out0);
}